// Round 9
// baseline (194.826 us; speedup 1.0000x reference)
//
#include <hip/hip_runtime.h>
#include <hip/hip_bf16.h>
#include <stdint.h>

#define B_ 4
#define T_ 8192
#define D_ 512
#define H_ 512
#define M_ (B_ * T_)          // 32768 rows
#define SEG 32                // scan segment length (t steps)
#define SPB 256               // segments per batch chain (T_/SEG)
#define NSEG (M_ / SEG)       // 1024 segments total

typedef __attribute__((ext_vector_type(8))) short short8;
typedef __attribute__((ext_vector_type(4))) float floatx4;
typedef __attribute__((ext_vector_type(2))) unsigned int uint2e;
typedef __attribute__((ext_vector_type(2))) float float2e;
typedef __attribute__((ext_vector_type(8))) unsigned short ushort8e;

__device__ __forceinline__ unsigned short f2bf(float f) {
    union { float f; unsigned int u; } v; v.f = f;
    unsigned int u = v.u;
    u += 0x7fffu + ((u >> 16) & 1u);   // RNE
    return (unsigned short)(u >> 16);
}
__device__ __forceinline__ float bf_lo(unsigned int u) {
    union { unsigned int i; float f; } a; a.i = u << 16; return a.f;
}
__device__ __forceinline__ float bf_hi(unsigned int u) {
    union { unsigned int i; float f; } a; a.i = u & 0xffff0000u; return a.f;
}
__device__ __forceinline__ unsigned int pk_cd(float c, float d) {
    return (unsigned int)f2bf(c) | ((unsigned int)f2bf(d) << 16);
}

// ---------------------------------------------------------------------------
// f32 -> bf16 converter: 8 elems/thread, 16-B stores, block-uniform branching
// ---------------------------------------------------------------------------
__global__ __launch_bounds__(256)
void conv_all(const float* __restrict__ x,
              const float* __restrict__ Wz,
              const float* __restrict__ Wh,
              unsigned short* __restrict__ xbf,
              unsigned short* __restrict__ Wf)
{
    const int X8 = M_ * D_ / 8;        // 2,097,152
    const int W8 = H_ * D_ / 8;        // 32,768
    int i = blockIdx.x * blockDim.x + threadIdx.x;
    const float* src; unsigned short* dst; int idx;
    if (i < X8)             { src = x;  dst = xbf;                  idx = i; }
    else if (i < X8 + W8)   { src = Wz; dst = Wf;                   idx = i - X8; }
    else if (i < X8 + 2*W8) { src = Wh; dst = Wf + (size_t)H_ * D_; idx = i - X8 - W8; }
    else return;
    float4 v0 = ((const float4*)src)[idx * 2];
    float4 v1 = ((const float4*)src)[idx * 2 + 1];
    ushort8e w;
    w[0] = f2bf(v0.x); w[1] = f2bf(v0.y); w[2] = f2bf(v0.z); w[3] = f2bf(v0.w);
    w[4] = f2bf(v1.x); w[5] = f2bf(v1.y); w[6] = f2bf(v1.z); w[7] = f2bf(v1.w);
    *(ushort8e*)&dst[idx * 8] = w;
}

// ---------------------------------------------------------------------------
// Dual GEMM (128m x 64h tile, z+h) + act epilogue + fused 32-t segment scan.
// Single-barrier LDS double-buffer K-loop. Sagg chain-major [b*512+h][256].
// ---------------------------------------------------------------------------
#define LDSB 35840     // union: 2x16 KB staging bufs | 128x68 dword cd tile

__global__ __launch_bounds__(256, 4)
void gemm_cd(const unsigned short* __restrict__ xbf,
             const unsigned short* __restrict__ Wf,   // rows [0:512)=Wz, [512:1024)=Wh
             const float* __restrict__ bz, const float* __restrict__ bh,
             unsigned int* __restrict__ cd,           // [M][512] (c,d) bf16-pair dwords
             float2* __restrict__ Sagg)               // [2048 chains][256 segs]
{
    __shared__ __align__(16) char smem[LDSB];
    unsigned short* lds = (unsigned short*)smem;      // staging (shorts)
    unsigned int*   cdl = (unsigned int*)smem;        // cd transpose tile (dwords)

    const int tid  = threadIdx.x;
    const int lane = tid & 63;
    const int wave = tid >> 6;
    const int xcd  = blockIdx.x & 7;
    const int nblk = (blockIdx.x >> 3) & 7;
    const int mblk = xcd * 32 + (blockIdx.x >> 6);
    const int m0 = mblk * 128;
    const int n0 = nblk * 64;
    const int wm = (wave >> 1) * 64;
    const int wn = (wave & 1) * 32;
    const int l15  = lane & 15;
    const int quad = lane >> 4;
    const int srow = lane >> 2;
    const int sp   = lane & 3;

    #define STAGE(p, kt)                                                          \
    {                                                                             \
        const int kb = (kt) * 32;                                                 \
        unsigned short* bb = lds + (p) * 8192;                                    \
        _Pragma("unroll")                                                         \
        for (int r = 0; r < 2; ++r) {                                             \
            const int chunk = r * 4 + wave;                                       \
            const int row   = chunk * 16 + srow;                                  \
            const int kp    = sp ^ (row & 3);                                     \
            __builtin_amdgcn_global_load_lds(                                     \
                (const __attribute__((address_space(1))) unsigned int*)           \
                    (xbf + (size_t)(m0 + row) * D_ + kb + kp * 8),                \
                (__attribute__((address_space(3))) unsigned int*)(bb + chunk * 512),\
                16, 0, 0);                                                        \
        }                                                                         \
        {                                                                         \
            const int row = wave * 16 + srow;                                     \
            const int kp  = sp ^ (row & 3);                                       \
            __builtin_amdgcn_global_load_lds(                                     \
                (const __attribute__((address_space(1))) unsigned int*)           \
                    (Wf + (size_t)(n0 + row) * D_ + kb + kp * 8),                 \
                (__attribute__((address_space(3))) unsigned int*)(bb + 4096 + wave * 512),\
                16, 0, 0);                                                        \
            __builtin_amdgcn_global_load_lds(                                     \
                (const __attribute__((address_space(1))) unsigned int*)           \
                    (Wf + (size_t)(512 + n0 + row) * D_ + kb + kp * 8),           \
                (__attribute__((address_space(3))) unsigned int*)(bb + 6144 + wave * 512),\
                16, 0, 0);                                                        \
        }                                                                         \
    }

    floatx4 acc_z[4][2], acc_h[4][2];
    #pragma unroll
    for (int i = 0; i < 4; ++i)
        #pragma unroll
        for (int j = 0; j < 2; ++j) { acc_z[i][j] = (floatx4)0.0f; acc_h[i][j] = (floatx4)0.0f; }

    STAGE(0, 0);

    for (int kt = 0; kt < 16; ++kt) {
        __syncthreads();
        const int base = (kt & 1) * 8192;
        short8 af[4], zf[2], hf[2];
        #pragma unroll
        for (int i = 0; i < 4; ++i) {
            const int ra = wm + i * 16 + l15;
            af[i] = *(const short8*)&lds[base + ra * 32 + ((quad ^ (ra & 3)) * 8)];
        }
        #pragma unroll
        for (int j = 0; j < 2; ++j) {
            const int rb = wn + j * 16 + l15;
            zf[j] = *(const short8*)&lds[base + 4096 + rb * 32 + ((quad ^ (rb & 3)) * 8)];
            hf[j] = *(const short8*)&lds[base + 6144 + rb * 32 + ((quad ^ (rb & 3)) * 8)];
        }
        if (kt < 15) STAGE((kt + 1) & 1, kt + 1);
        #pragma unroll
        for (int i = 0; i < 4; ++i)
            #pragma unroll
            for (int j = 0; j < 2; ++j) {
                acc_z[i][j] = __builtin_amdgcn_mfma_f32_16x16x32_bf16(zf[j], af[i], acc_z[i][j], 0, 0, 0);
                acc_h[i][j] = __builtin_amdgcn_mfma_f32_16x16x32_bf16(hf[j], af[i], acc_h[i][j], 0, 0, 0);
            }
    }

    __syncthreads();   // staging LDS dead; reuse as cd transpose tile

    #pragma unroll
    for (int j = 0; j < 2; ++j) {
        const int hlb = wn + j * 16 + quad * 4;
        const float4 bzv = *(const float4*)&bz[n0 + hlb];
        const float4 bhv = *(const float4*)&bh[n0 + hlb];
        #pragma unroll
        for (int i = 0; i < 4; ++i) {
            const int mloc = wm + i * 16 + l15;
            uint4 w;
            #pragma unroll
            for (int r = 0; r < 4; ++r) {
                float kz = acc_z[i][j][r] + ((const float*)&bzv)[r];
                float hp = acc_h[i][j][r] + ((const float*)&bhv)[r];
                float c  = __builtin_amdgcn_rcpf(1.0f + __expf(kz));   // sigmoid(-kz), raw rcp
                float g  = (hp >= 0.0f) ? (hp + 0.5f)
                                        : __builtin_amdgcn_rcpf(1.0f + __expf(-hp));
                float d  = (1.0f - c) * g;
                ((unsigned int*)&w)[r] = pk_cd(c, d);
            }
            *(uint4*)&cd[(size_t)(m0 + mloc) * H_ + n0 + hlb] = w;
            *(uint4*)&cdl[mloc * 68 + hlb] = w;
        }
    }

    __syncthreads();

    // segment scans: wave = 32-t segment, lane = h column; chain-major store
    {
        float C = 1.0f, Dv = 0.0f;
        const int t0 = wave * 32;
        #pragma unroll
        for (int t = 0; t < 32; ++t) {
            unsigned int u = cdl[(t0 + t) * 68 + lane];
            float c = bf_lo(u), d = bf_hi(u);
            Dv = fmaf(c, Dv, d);
            C *= c;
        }
        const int chain = (m0 >> 13) * 512 + n0 + lane;      // b*512 + h
        const int seg   = ((m0 >> 5) & 255) + wave;          // in-batch segment
        Sagg[(size_t)chain * SPB + seg] = make_float2(C, Dv);
    }
    #undef STAGE
}

// ---------------------------------------------------------------------------
// inter-segment scan: one WAVE per (b,h) chain; lane l holds segs 4l..4l+3.
// Hseg written SEG-MAJOR [b][s][h] so apply's reads coalesce (scatter here,
// where total traffic is tiny).
// ---------------------------------------------------------------------------
__global__ __launch_bounds__(256)
void interseg(const float* __restrict__ h_prev,
              const float2* __restrict__ Sagg,
              float* __restrict__ Hseg)
{
    const int chain = blockIdx.x * 4 + (threadIdx.x >> 6);
    const int lane  = threadIdx.x & 63;
    const int b = chain >> 9;
    const int h = chain & 511;
    const float2* spp = Sagg + (size_t)chain * SPB + lane * 4;
    float4 q0 = *(const float4*)&spp[0];   // (C0,D0,C1,D1)
    float4 q1 = *(const float4*)&spp[2];   // (C2,D2,C3,D3)
    // lane-local composition in time order
    float C = q0.x, D = q0.y;
    D = fmaf(q0.z, D, q0.w);  C *= q0.z;
    D = fmaf(q1.x, D, q1.y);  C *= q1.x;
    D = fmaf(q1.z, D, q1.w);  C *= q1.z;
    // inclusive wave scan
    #pragma unroll
    for (int off = 1; off < 64; off <<= 1) {
        float Cp = __shfl_up(C, off, 64);
        float Dp = __shfl_up(D, off, 64);
        if (lane >= off) { D = fmaf(C, Dp, D); C *= Cp; }
    }
    // exclusive
    float Ce = __shfl_up(C, 1, 64);
    float De = __shfl_up(D, 1, 64);
    if (lane == 0) { Ce = 1.0f; De = 0.0f; }
    const float h0 = h_prev[chain];
    float hs = fmaf(Ce, h0, De);
    float* hb = Hseg + ((size_t)b * SPB + lane * 4) * H_ + h;   // [b][s][h]
    hb[0]            = hs;
    hs = fmaf(q0.x, hs, q0.y); hb[H_]     = hs;
    hs = fmaf(q0.z, hs, q0.w); hb[2 * H_] = hs;
    hs = fmaf(q1.x, hs, q1.y); hb[3 * H_] = hs;
}

// ---------------------------------------------------------------------------
// final apply: 1024 blocks (one per 32-t segment) x 256 thr x 2 h.
// Coalesced Hseg (seg-major), plain loads, nontemporal stores.
// ---------------------------------------------------------------------------
__global__ __launch_bounds__(256)
void apply_scan(const unsigned int* __restrict__ cd,
                const float* __restrict__ Hseg,
                float* __restrict__ out)
{
    const int sg = blockIdx.x;            // global segment = b*256+s
    const int h  = threadIdx.x * 2;
    float2 hsv = *(const float2*)&Hseg[(size_t)sg * H_ + h];
    float hs0 = hsv.x, hs1 = hsv.y;
    const unsigned int* base = cd + (size_t)sg * SEG * H_ + h;
    float* ob = out + (size_t)sg * SEG * H_ + h;
    #pragma unroll
    for (int t = 0; t < SEG; ++t) {
        uint2e v = *(const uint2e*)(base + (size_t)t * H_);
        hs0 = fmaf(bf_lo(v.x), hs0, bf_hi(v.x));
        hs1 = fmaf(bf_lo(v.y), hs1, bf_hi(v.y));
        float2e o; o.x = hs0; o.y = hs1;
        __builtin_nontemporal_store(o, (float2e*)(ob + (size_t)t * H_));
    }
}

// ---------------------------------------------------------------------------
extern "C" void kernel_launch(void* const* d_in, const int* in_sizes, int n_in,
                              void* d_out, int out_size, void* d_ws, size_t ws_size,
                              hipStream_t stream)
{
    const float* x      = (const float*)d_in[0];
    const float* h_prev = (const float*)d_in[1];
    const float* W_h    = (const float*)d_in[2];
    const float* b_h    = (const float*)d_in[3];
    const float* W_z    = (const float*)d_in[4];
    const float* b_z    = (const float*)d_in[5];
    float* out = (float*)d_out;

    // xbf lives in d_out (dead until apply_scan overwrites all of it)
    unsigned short* xbf = (unsigned short*)d_out;

    char* ws = (char*)d_ws;
    unsigned int* cd = (unsigned int*)ws;                       // 67.1 MB
    size_t cd_bytes = (size_t)M_ * H_ * 4;
    unsigned short* Wf = (unsigned short*)(ws + cd_bytes);      // 1 MB
    size_t wf_bytes = (size_t)2 * H_ * D_ * sizeof(unsigned short);
    float2* Sagg = (float2*)(ws + cd_bytes + wf_bytes);         // 4 MB
    float*  Hseg = (float*)((char*)Sagg + (size_t)2048 * SPB * sizeof(float2)); // 2 MB

    // 0) convert inputs to bf16 (8 elems/thread)
    {
        int total8 = M_ * D_ / 8 + 2 * (H_ * D_ / 8);
        conv_all<<<dim3((total8 + 255) / 256), dim3(256), 0, stream>>>(x, W_z, W_h, xbf, Wf);
    }
    // 1) dual GEMM + activation + fused segment aggregates (chain-major Sagg)
    gemm_cd<<<dim3((M_ / 128) * (H_ / 64)), dim3(256), 0, stream>>>(
        xbf, Wf, b_z, b_h, cd, Sagg);
    // 2) inter-segment scan, wave-per-chain; Hseg seg-major
    interseg<<<dim3(512), dim3(256), 0, stream>>>(h_prev, Sagg, Hseg);
    // 3) final apply -> d_out
    apply_scan<<<dim3(NSEG), dim3(256), 0, stream>>>(cd, Hseg, out);
}